// Round 8
// baseline (606.543 us; speedup 1.0000x reference)
//
#include <hip/hip_runtime.h>

typedef short bf16x8 __attribute__((ext_vector_type(8)));
typedef float f32x4 __attribute__((ext_vector_type(4)));

constexpr int NB1    = 131073;   // num_bonds + 1 (row 131072 = zero sentinel)
constexpr int SENT   = 131072;
constexpr int NATOMS = 65536;
constexpr int AFD    = 133;
constexpr int CFD    = 147;
constexpr int DH     = 300;
constexpr int GFD    = 2048;
constexpr int NMOLS  = 4096;
constexpr int OUTD   = DH + GFD; // 2348
constexpr int HS     = 320;      // h/y/inp row stride (bf16) = padded N
constexpr int KP1    = 160;      // padded CFD / AFD
constexpr int KP2    = 320;      // padded DH
constexpr int KPC    = 480;      // padded concat K for atom GEMM
constexpr int LSTR   = 328;      // LDS A-tile row stride (320 + 8 pad)
constexpr int LSTRC  = 488;      // LDS A-tile row stride for atom (480 + 8)

__device__ __forceinline__ unsigned short f2b(float f) {
    unsigned u = __float_as_uint(f);
    u += 0x7fffu + ((u >> 16) & 1u);
    return (unsigned short)(u >> 16);
}
__device__ __forceinline__ float blo(unsigned x) { return __uint_as_float(x << 16); }
__device__ __forceinline__ float bhi(unsigned x) { return __uint_as_float(x & 0xffff0000u); }
__device__ __forceinline__ unsigned pk2(float hi, float lo) {
    return ((unsigned)f2b(hi) << 16) | (unsigned)f2b(lo);
}
__device__ __forceinline__ unsigned pairsum4(unsigned a, unsigned b, unsigned c, unsigned d) {
    float lo = blo(a) + blo(b) + blo(c) + blo(d);
    float hi = bhi(a) + bhi(b) + bhi(c) + bhi(d);
    return pk2(hi, lo);
}
__device__ __forceinline__ bf16x8 asbf(uint4 u) {
    union { uint4 u; bf16x8 b; } c; c.u = u; return c.b;
}

// ===================== PRIMARY PATH (BM=32, 4 blocks/CU) =====================

// ---- K1: inp = fini @ Wi^T (raw); y1 = relu(inp) @ Wh^T (raw) ----
__global__ __launch_bounds__(256, 4) void fused_in(
    const float* __restrict__ fini,          // [NB1][147] fp32
    const unsigned short* __restrict__ WiP,  // [320][160] bf16
    const unsigned short* __restrict__ WhP,  // [320][320] bf16
    unsigned short* __restrict__ inp,        // [NB1][320] bf16 raw
    unsigned short* __restrict__ y1)         // [NB1][320] bf16 raw
{
    __shared__ __align__(16) short As[32 * LSTR];  // 21 KB
    const int tid = threadIdx.x, w = tid >> 6, lane = tid & 63;
    const int ml = lane & 15, kl = lane >> 4;
    const int m0 = blockIdx.x * 32;

    f32x4 acc[2][5];
#pragma unroll
    for (int mt = 0; mt < 2; ++mt)
#pragma unroll
        for (int nt = 0; nt < 5; ++nt) acc[mt][nt] = (f32x4){0.f, 0.f, 0.f, 0.f};

    // ---- phase 1: fragment-direct A from fini fp32, K=160 ----
    const float* fr[2];
#pragma unroll
    for (int mt = 0; mt < 2; ++mt) {
        int r = m0 + mt * 16 + ml;
        fr[mt] = fini + (size_t)(r < NB1 ? r : SENT) * CFD + kl * 8;
    }
    const unsigned short* bpi = WiP + (size_t)(w * 80 + ml) * KP1 + kl * 8;
#pragma unroll
    for (int c = 0; c < 5; ++c) {
        uint4 B[5];
#pragma unroll
        for (int nt = 0; nt < 5; ++nt) B[nt] = *(const uint4*)(bpi + c * 32 + nt * 16 * KP1);
        bf16x8 af[2];
#pragma unroll
        for (int mt = 0; mt < 2; ++mt) {
            union { short s[8]; bf16x8 x; } u;
            if (c < 4) {
#pragma unroll
                for (int j = 0; j < 8; ++j) u.s[j] = (short)f2b(fr[mt][c * 32 + j]);
            } else {
#pragma unroll
                for (int j = 0; j < 8; ++j) {
                    int k = 128 + kl * 8 + j;
                    u.s[j] = (short)f2b(k < CFD ? fr[mt][c * 32 + j] : 0.f);
                }
            }
            af[mt] = u.x;
        }
#pragma unroll
        for (int mt = 0; mt < 2; ++mt)
#pragma unroll
            for (int nt = 0; nt < 5; ++nt)
                acc[mt][nt] = __builtin_amdgcn_mfma_f32_16x16x32_bf16(af[mt], asbf(B[nt]), acc[mt][nt], 0, 0, 0);
    }

    // ---- epilogue 1: write inp (raw) + stage relu(inp) tile into LDS ----
#pragma unroll
    for (int mt = 0; mt < 2; ++mt)
#pragma unroll
        for (int reg = 0; reg < 4; ++reg) {
            int lr = mt * 16 + kl * 4 + reg;
            int m = m0 + lr;
#pragma unroll
            for (int nt = 0; nt < 5; ++nt) {
                int col = w * 80 + nt * 16 + ml;
                float v = acc[mt][nt][reg];
                if (m < NB1) inp[(size_t)m * HS + col] = f2b(v);
                As[lr * LSTR + col] = (short)f2b(v > 0.f ? v : 0.f);
            }
        }
    __syncthreads();   // the ONLY barrier

    // ---- phase 2: y1 = LDS-tile @ Wh^T, K=320 ----
#pragma unroll
    for (int mt = 0; mt < 2; ++mt)
#pragma unroll
        for (int nt = 0; nt < 5; ++nt) acc[mt][nt] = (f32x4){0.f, 0.f, 0.f, 0.f};
    const unsigned short* bph = WhP + (size_t)(w * 80 + ml) * KP2 + kl * 8;
#pragma unroll
    for (int c = 0; c < 10; ++c) {
        uint4 B[5];
#pragma unroll
        for (int nt = 0; nt < 5; ++nt) B[nt] = *(const uint4*)(bph + c * 32 + nt * 16 * KP2);
        bf16x8 af[2];
#pragma unroll
        for (int mt = 0; mt < 2; ++mt)
            af[mt] = *(const bf16x8*)&As[(mt * 16 + ml) * LSTR + c * 32 + kl * 8];
#pragma unroll
        for (int mt = 0; mt < 2; ++mt)
#pragma unroll
            for (int nt = 0; nt < 5; ++nt)
                acc[mt][nt] = __builtin_amdgcn_mfma_f32_16x16x32_bf16(af[mt], asbf(B[nt]), acc[mt][nt], 0, 0, 0);
    }
#pragma unroll
    for (int mt = 0; mt < 2; ++mt)
#pragma unroll
        for (int reg = 0; reg < 4; ++reg) {
            int m = m0 + mt * 16 + kl * 4 + reg;
            if (m < NB1) {
#pragma unroll
                for (int nt = 0; nt < 5; ++nt)
                    y1[(size_t)m * HS + w * 80 + nt * 16 + ml] = f2b(acc[mt][nt][reg]);
            }
        }
}

// ---- K2: ydst = relu(inp + sum_4 ysrc[map]) @ Wh^T (h-tile staged in LDS) ----
__global__ __launch_bounds__(256, 4) void fused_mid(
    const unsigned short* __restrict__ ysrc,
    const unsigned short* __restrict__ inp,
    const int* __restrict__ mapping,
    const unsigned short* __restrict__ WhP,
    unsigned short* __restrict__ ydst)
{
    __shared__ __align__(16) short As[32 * LSTR];  // 21 KB
    const int tid = threadIdx.x, w = tid >> 6, lane = tid & 63;
    const int ml = lane & 15, kl = lane >> 4;
    const int m0 = blockIdx.x * 32;

    // ---- stage h-tile: 8 threads/row, 5 uint4-segments each ----
    {
        const int sr = tid >> 3, sg = tid & 7;
        int srow = m0 + sr;
        int crow = srow < NB1 ? srow : SENT;
        int4 mp = *(const int4*)(mapping + (size_t)crow * 4);
        const unsigned short* r0 = ysrc + (size_t)(mp.x < 0 ? SENT : mp.x) * HS;
        const unsigned short* r1 = ysrc + (size_t)(mp.y < 0 ? SENT : mp.y) * HS;
        const unsigned short* r2 = ysrc + (size_t)(mp.z < 0 ? SENT : mp.z) * HS;
        const unsigned short* r3 = ysrc + (size_t)(mp.w < 0 ? SENT : mp.w) * HS;
        const unsigned short* ip = inp + (size_t)crow * HS;
#pragma unroll
        for (int s = 0; s < 5; ++s) {
            int off = (s * 8 + sg) * 8;
            uint4 a = *(const uint4*)(r0 + off);
            uint4 b = *(const uint4*)(r1 + off);
            uint4 c = *(const uint4*)(r2 + off);
            uint4 d = *(const uint4*)(r3 + off);
            uint4 e = *(const uint4*)(ip + off);
            uint4 o;
            float lo, hi;
            lo = blo(a.x)+blo(b.x)+blo(c.x)+blo(d.x)+blo(e.x); hi = bhi(a.x)+bhi(b.x)+bhi(c.x)+bhi(d.x)+bhi(e.x);
            o.x = pk2(hi > 0.f ? hi : 0.f, lo > 0.f ? lo : 0.f);
            lo = blo(a.y)+blo(b.y)+blo(c.y)+blo(d.y)+blo(e.y); hi = bhi(a.y)+bhi(b.y)+bhi(c.y)+bhi(d.y)+bhi(e.y);
            o.y = pk2(hi > 0.f ? hi : 0.f, lo > 0.f ? lo : 0.f);
            lo = blo(a.z)+blo(b.z)+blo(c.z)+blo(d.z)+blo(e.z); hi = bhi(a.z)+bhi(b.z)+bhi(c.z)+bhi(d.z)+bhi(e.z);
            o.z = pk2(hi > 0.f ? hi : 0.f, lo > 0.f ? lo : 0.f);
            lo = blo(a.w)+blo(b.w)+blo(c.w)+blo(d.w)+blo(e.w); hi = bhi(a.w)+bhi(b.w)+bhi(c.w)+bhi(d.w)+bhi(e.w);
            o.w = pk2(hi > 0.f ? hi : 0.f, lo > 0.f ? lo : 0.f);
            *(uint4*)&As[sr * LSTR + off] = o;
        }
    }
    __syncthreads();   // the ONLY barrier

    f32x4 acc[2][5];
#pragma unroll
    for (int mt = 0; mt < 2; ++mt)
#pragma unroll
        for (int nt = 0; nt < 5; ++nt) acc[mt][nt] = (f32x4){0.f, 0.f, 0.f, 0.f};
    const unsigned short* bph = WhP + (size_t)(w * 80 + ml) * KP2 + kl * 8;
#pragma unroll
    for (int c = 0; c < 10; ++c) {
        uint4 B[5];
#pragma unroll
        for (int nt = 0; nt < 5; ++nt) B[nt] = *(const uint4*)(bph + c * 32 + nt * 16 * KP2);
        bf16x8 af[2];
#pragma unroll
        for (int mt = 0; mt < 2; ++mt)
            af[mt] = *(const bf16x8*)&As[(mt * 16 + ml) * LSTR + c * 32 + kl * 8];
#pragma unroll
        for (int mt = 0; mt < 2; ++mt)
#pragma unroll
            for (int nt = 0; nt < 5; ++nt)
                acc[mt][nt] = __builtin_amdgcn_mfma_f32_16x16x32_bf16(af[mt], asbf(B[nt]), acc[mt][nt], 0, 0, 0);
    }
#pragma unroll
    for (int mt = 0; mt < 2; ++mt)
#pragma unroll
        for (int reg = 0; reg < 4; ++reg) {
            int m = m0 + mt * 16 + kl * 4 + reg;
            if (m < NB1) {
#pragma unroll
                for (int nt = 0; nt < 5; ++nt)
                    ydst[(size_t)m * HS + w * 80 + nt * 16 + ml] = f2b(acc[mt][nt][reg]);
            }
        }
}

// ---- K3: h2 = relu(inp + sum_4 y2[map]) ----
__global__ __launch_bounds__(256) void gather_bond(
    const unsigned short* __restrict__ y, const unsigned short* __restrict__ inp,
    const int* __restrict__ mapping, unsigned short* __restrict__ hout)
{
    int t = blockIdx.x * 256 + threadIdx.x;
    int row = t >> 3, g = t & 7;
    if (row >= NB1) return;
    int4 mp = *(const int4*)(mapping + (size_t)row * 4);
    const unsigned short* r0 = y + (size_t)(mp.x < 0 ? SENT : mp.x) * HS;
    const unsigned short* r1 = y + (size_t)(mp.y < 0 ? SENT : mp.y) * HS;
    const unsigned short* r2 = y + (size_t)(mp.z < 0 ? SENT : mp.z) * HS;
    const unsigned short* r3 = y + (size_t)(mp.w < 0 ? SENT : mp.w) * HS;
    const unsigned short* ip = inp + (size_t)row * HS;
    unsigned short* op = hout + (size_t)row * HS;
#pragma unroll
    for (int s = 0; s < 5; ++s) {
        int off = (g + s * 8) * 8;
        uint4 a = *(const uint4*)(r0 + off);
        uint4 b = *(const uint4*)(r1 + off);
        uint4 c = *(const uint4*)(r2 + off);
        uint4 d = *(const uint4*)(r3 + off);
        uint4 e = *(const uint4*)(ip + off);
        uint4 o;
        float lo, hi;
        lo = blo(a.x)+blo(b.x)+blo(c.x)+blo(d.x)+blo(e.x); hi = bhi(a.x)+bhi(b.x)+bhi(c.x)+bhi(d.x)+bhi(e.x);
        o.x = pk2(hi > 0.f ? hi : 0.f, lo > 0.f ? lo : 0.f);
        lo = blo(a.y)+blo(b.y)+blo(c.y)+blo(d.y)+blo(e.y); hi = bhi(a.y)+bhi(b.y)+bhi(c.y)+bhi(d.y)+bhi(e.y);
        o.y = pk2(hi > 0.f ? hi : 0.f, lo > 0.f ? lo : 0.f);
        lo = blo(a.z)+blo(b.z)+blo(c.z)+blo(d.z)+blo(e.z); hi = bhi(a.z)+bhi(b.z)+bhi(c.z)+bhi(d.z)+bhi(e.z);
        o.z = pk2(hi > 0.f ? hi : 0.f, lo > 0.f ? lo : 0.f);
        lo = blo(a.w)+blo(b.w)+blo(c.w)+blo(d.w)+blo(e.w); hi = bhi(a.w)+bhi(b.w)+bhi(c.w)+bhi(d.w)+bhi(e.w);
        o.w = pk2(hi > 0.f ? hi : 0.f, lo > 0.f ? lo : 0.f);
        *(uint4*)(op + off) = o;
    }
}

// ---- K4: out[mol][0:300] = mean_16 relu([atomf | sum_4 h[a2b]] @ WoC^T + bo) ----
__global__ __launch_bounds__(256, 4) void fused_atom(
    const float* __restrict__ atomf,         // [NATOMS][133] fp32
    const unsigned short* __restrict__ h,    // [NB1][320] bf16
    const int* __restrict__ a2b,             // [NATOMS][4]
    const unsigned short* __restrict__ WoC,  // [320][480] bf16
    const float* __restrict__ bo,            // [300]
    float* __restrict__ out)                 // [NMOLS][OUTD]
{
    __shared__ __align__(16) short As[32 * LSTRC];  // 30.5 KB
    const int tid = threadIdx.x, w = tid >> 6, lane = tid & 63;
    const int ml = lane & 15, kl = lane >> 4;
    const int m0 = blockIdx.x * 32;

    // ---- stage [atomf | gather-sum h] tile: 8 threads/row, 8 segments (guarded) ----
    {
        const int sr = tid >> 3, sg = tid & 7;
        int row = m0 + sr;
        int4 mp = *(const int4*)(a2b + (size_t)row * 4);
        const unsigned short* r0 = h + (size_t)(mp.x < 0 ? SENT : mp.x) * HS;
        const unsigned short* r1 = h + (size_t)(mp.y < 0 ? SENT : mp.y) * HS;
        const unsigned short* r2 = h + (size_t)(mp.z < 0 ? SENT : mp.z) * HS;
        const unsigned short* r3 = h + (size_t)(mp.w < 0 ? SENT : mp.w) * HS;
        const float* fp = atomf + (size_t)row * AFD;
#pragma unroll
        for (int s = 0; s < 8; ++s) {
            int k0 = (s * 8 + sg) * 8;
            if (k0 >= KPC) continue;
            if (k0 < KP1) {
                union { short s8[8]; uint4 u; } u;
#pragma unroll
                for (int j = 0; j < 8; ++j) {
                    int k = k0 + j;
                    u.s8[j] = (short)f2b(k < AFD ? fp[k] : 0.f);
                }
                *(uint4*)&As[sr * LSTRC + k0] = u.u;
            } else {
                int off = k0 - KP1;
                uint4 a = *(const uint4*)(r0 + off);
                uint4 b = *(const uint4*)(r1 + off);
                uint4 c = *(const uint4*)(r2 + off);
                uint4 d = *(const uint4*)(r3 + off);
                uint4 o;
                o.x = pairsum4(a.x, b.x, c.x, d.x);
                o.y = pairsum4(a.y, b.y, c.y, d.y);
                o.z = pairsum4(a.z, b.z, c.z, d.z);
                o.w = pairsum4(a.w, b.w, c.w, d.w);
                *(uint4*)&As[sr * LSTRC + k0] = o;
            }
        }
    }
    __syncthreads();   // the ONLY barrier

    f32x4 acc[2][5];
#pragma unroll
    for (int mt = 0; mt < 2; ++mt)
#pragma unroll
        for (int nt = 0; nt < 5; ++nt) acc[mt][nt] = (f32x4){0.f, 0.f, 0.f, 0.f};
    const unsigned short* bp = WoC + (size_t)(w * 80 + ml) * KPC + kl * 8;
#pragma unroll
    for (int c = 0; c < 15; ++c) {
        uint4 B[5];
#pragma unroll
        for (int nt = 0; nt < 5; ++nt) B[nt] = *(const uint4*)(bp + c * 32 + nt * 16 * KPC);
        bf16x8 af[2];
#pragma unroll
        for (int mt = 0; mt < 2; ++mt)
            af[mt] = *(const bf16x8*)&As[(mt * 16 + ml) * LSTRC + c * 32 + kl * 8];
#pragma unroll
        for (int mt = 0; mt < 2; ++mt)
#pragma unroll
            for (int nt = 0; nt < 5; ++nt)
                acc[mt][nt] = __builtin_amdgcn_mfma_f32_16x16x32_bf16(af[mt], asbf(B[nt]), acc[mt][nt], 0, 0, 0);
    }

    // ---- epilogue: bias + relu + mean over each 16-row m-tile (= 1 molecule) ----
#pragma unroll
    for (int mt = 0; mt < 2; ++mt) {
        int mol = blockIdx.x * 2 + mt;
#pragma unroll
        for (int nt = 0; nt < 5; ++nt) {
            int n = w * 80 + nt * 16 + ml;
            float bias = (n < DH) ? bo[n] : 0.f;
            float s = 0.f;
#pragma unroll
            for (int reg = 0; reg < 4; ++reg) {
                float v = acc[mt][nt][reg] + bias;
                s += (v > 0.f ? v : 0.f);
            }
            s += __shfl_down(s, 32, 64);
            s += __shfl_down(s, 16, 64);
            if (kl == 0 && n < DH) out[(size_t)mol * OUTD + n] = s * (1.f / 16.f);
        }
    }
}

// ===================== FALLBACK (ws < 252 MB) =====================

__global__ __launch_bounds__(256, 3) void bond_gemm_fb(
    const float* __restrict__ fini, const unsigned short* __restrict__ hsrc,
    const int* __restrict__ mapping, const unsigned short* __restrict__ WiP,
    const unsigned short* __restrict__ WhP, unsigned short* __restrict__ hdst,
    int do_msg)
{
    const int tid = threadIdx.x, wv = tid >> 6, lane = tid & 63;
    const int ml = lane & 15, kh = lane >> 4;
    const int m0 = blockIdx.x * 64 + wv * 16;
    const int mrow = m0 + ml;
    const int mrowc = mrow < NB1 ? mrow : SENT;

    f32x4 acc[20];
#pragma unroll
    for (int nt = 0; nt < 20; ++nt) acc[nt] = (f32x4){0.f, 0.f, 0.f, 0.f};
    {
        const float* fp = fini + (size_t)mrowc * CFD;
#pragma unroll
        for (int c = 0; c < 5; ++c) {
            union { short s[8]; bf16x8 x; } u;
#pragma unroll
            for (int j = 0; j < 8; ++j) {
                int k = c * 32 + kh * 8 + j;
                u.s[j] = (short)f2b(k < CFD ? fp[k] : 0.f);
            }
            const unsigned short* bp = WiP + ml * KP1 + c * 32 + kh * 8;
#pragma unroll
            for (int nt = 0; nt < 20; ++nt)
                acc[nt] = __builtin_amdgcn_mfma_f32_16x16x32_bf16(u.x, *(const bf16x8*)(bp + nt * 16 * KP1), acc[nt], 0, 0, 0);
        }
    }
    if (do_msg) {
        int4 mp = *(const int4*)(mapping + (size_t)mrowc * 4);
        const unsigned short* g0 = hsrc + (size_t)(mp.x < 0 ? SENT : mp.x) * HS + kh * 8;
        const unsigned short* g1 = hsrc + (size_t)(mp.y < 0 ? SENT : mp.y) * HS + kh * 8;
        const unsigned short* g2 = hsrc + (size_t)(mp.z < 0 ? SENT : mp.z) * HS + kh * 8;
        const unsigned short* g3 = hsrc + (size_t)(mp.w < 0 ? SENT : mp.w) * HS + kh * 8;
#pragma unroll
        for (int c = 0; c < 10; ++c) {
            uint4 a = *(const uint4*)(g0 + c * 32);
            uint4 b = *(const uint4*)(g1 + c * 32);
            uint4 cc = *(const uint4*)(g2 + c * 32);
            uint4 d = *(const uint4*)(g3 + c * 32);
            uint4 o;
            o.x = pairsum4(a.x, b.x, cc.x, d.x);
            o.y = pairsum4(a.y, b.y, cc.y, d.y);
            o.z = pairsum4(a.z, b.z, cc.z, d.z);
            o.w = pairsum4(a.w, b.w, cc.w, d.w);
            const unsigned short* bp = WhP + ml * KP2 + c * 32 + kh * 8;
#pragma unroll
            for (int nt = 0; nt < 20; ++nt)
                acc[nt] = __builtin_amdgcn_mfma_f32_16x16x32_bf16(asbf(o), *(const bf16x8*)(bp + nt * 16 * KP2), acc[nt], 0, 0, 0);
        }
    }
#pragma unroll
    for (int nt = 0; nt < 20; ++nt) {
        int n = nt * 16 + ml;
#pragma unroll
        for (int reg = 0; reg < 4; ++reg) {
            int m = m0 + kh * 4 + reg;
            if (m < NB1) {
                float v = acc[nt][reg];
                hdst[(size_t)m * HS + n] = f2b(v > 0.f ? v : 0.f);
            }
        }
    }
}

__global__ __launch_bounds__(256, 3) void atom_gemm_fb(
    const float* __restrict__ atomf, const unsigned short* __restrict__ hsrc,
    const int* __restrict__ a2b, const unsigned short* __restrict__ WoA,
    const unsigned short* __restrict__ WoB, const float* __restrict__ bo,
    float* __restrict__ out)
{
    const int tid = threadIdx.x, wv = tid >> 6, lane = tid & 63;
    const int ml = lane & 15, kh = lane >> 4;
    const int m0 = blockIdx.x * 64 + wv * 16;
    const int arow = m0 + ml;

    f32x4 acc[20];
#pragma unroll
    for (int nt = 0; nt < 20; ++nt) acc[nt] = (f32x4){0.f, 0.f, 0.f, 0.f};
    {
        const float* fp = atomf + (size_t)arow * AFD;
#pragma unroll
        for (int c = 0; c < 5; ++c) {
            union { short s[8]; bf16x8 x; } u;
#pragma unroll
            for (int j = 0; j < 8; ++j) {
                int k = c * 32 + kh * 8 + j;
                u.s[j] = (short)f2b(k < AFD ? fp[k] : 0.f);
            }
            const unsigned short* bp = WoA + ml * KP1 + c * 32 + kh * 8;
#pragma unroll
            for (int nt = 0; nt < 20; ++nt)
                acc[nt] = __builtin_amdgcn_mfma_f32_16x16x32_bf16(u.x, *(const bf16x8*)(bp + nt * 16 * KP1), acc[nt], 0, 0, 0);
        }
    }
    {
        int4 mp = *(const int4*)(a2b + (size_t)arow * 4);
        const unsigned short* g0 = hsrc + (size_t)(mp.x < 0 ? SENT : mp.x) * HS + kh * 8;
        const unsigned short* g1 = hsrc + (size_t)(mp.y < 0 ? SENT : mp.y) * HS + kh * 8;
        const unsigned short* g2 = hsrc + (size_t)(mp.z < 0 ? SENT : mp.z) * HS + kh * 8;
        const unsigned short* g3 = hsrc + (size_t)(mp.w < 0 ? SENT : mp.w) * HS + kh * 8;
#pragma unroll
        for (int c = 0; c < 10; ++c) {
            uint4 a = *(const uint4*)(g0 + c * 32);
            uint4 b = *(const uint4*)(g1 + c * 32);
            uint4 cc = *(const uint4*)(g2 + c * 32);
            uint4 d = *(const uint4*)(g3 + c * 32);
            uint4 o;
            o.x = pairsum4(a.x, b.x, cc.x, d.x);
            o.y = pairsum4(a.y, b.y, cc.y, d.y);
            o.z = pairsum4(a.z, b.z, cc.z, d.z);
            o.w = pairsum4(a.w, b.w, cc.w, d.w);
            const unsigned short* bp = WoB + ml * KP2 + c * 32 + kh * 8;
#pragma unroll
            for (int nt = 0; nt < 20; ++nt)
                acc[nt] = __builtin_amdgcn_mfma_f32_16x16x32_bf16(asbf(o), *(const bf16x8*)(bp + nt * 16 * KP2), acc[nt], 0, 0, 0);
        }
    }
    const int mol = blockIdx.x * 4 + wv;
#pragma unroll
    for (int nt = 0; nt < 20; ++nt) {
        int n = nt * 16 + ml;
        float bias = (n < DH) ? bo[n] : 0.f;
        float s = 0.f;
#pragma unroll
        for (int reg = 0; reg < 4; ++reg) {
            float v = acc[nt][reg] + bias;
            s += (v > 0.f ? v : 0.f);
        }
        s += __shfl_down(s, 32, 64);
        s += __shfl_down(s, 16, 64);
        if (kh == 0 && n < DH) out[(size_t)mol * OUTD + n] = s * (1.f / 16.f);
    }
}

// ===================== shared prep / copy =====================

__global__ void prep_w(const float* __restrict__ Wi, const float* __restrict__ Wh,
                       const float* __restrict__ Wo, unsigned short* __restrict__ wb, int mode) {
    int t = blockIdx.x * blockDim.x + threadIdx.x;
    if (t >= 307200) return;
    float v = 0.f;
    if (t < 51200) {                       // WiP [320][160]
        int n = t / 160, k = t % 160;
        if (n < DH && k < CFD) v = Wi[n * CFD + k];
    } else if (t < 153600) {               // WhP [320][320]
        int q = t - 51200; int n = q / 320, k = q % 320;
        if (n < DH && k < DH) v = Wh[n * DH + k];
    } else if (mode) {                     // WoC [320][480]
        int q = t - 153600; int n = q / 480, k = q % 480;
        if (n < DH) {
            if (k < AFD) v = Wo[n * 433 + k];
            else if (k >= 160 && k < 460) v = Wo[n * 433 + AFD + (k - 160)];
        }
    } else if (t < 204800) {               // WoA [320][160]
        int q = t - 153600; int n = q / 160, k = q % 160;
        if (n < DH && k < AFD) v = Wo[n * 433 + k];
    } else {                               // WoB [320][320]
        int q = t - 204800; int n = q / 320, k = q % 320;
        if (n < DH && k < DH) v = Wo[n * 433 + AFD + k];
    }
    wb[t] = f2b(v);
}

__global__ void copy_gf(const float4* __restrict__ gf, float* __restrict__ out) {
    int t = blockIdx.x * blockDim.x + threadIdx.x;
    if (t >= NMOLS * (GFD / 4)) return;
    int mol = t >> 9;
    int g4 = t & 511;
    float4 v = gf[t];
    *(float4*)(out + (size_t)mol * OUTD + DH + g4 * 4) = v;
}

extern "C" void kernel_launch(void* const* d_in, const int* in_sizes, int n_in,
                              void* d_out, int out_size, void* d_ws, size_t ws_size,
                              hipStream_t stream) {
    const float* atomf   = (const float*)d_in[0];
    const float* fini    = (const float*)d_in[1];
    const int*   a2b     = (const int*)d_in[2];
    const int*   mapping = (const int*)d_in[3];
    const float* gf      = (const float*)d_in[4];
    const float* W_i     = (const float*)d_in[5];
    const float* W_h     = (const float*)d_in[6];
    const float* W_o     = (const float*)d_in[7];
    const float* b_o     = (const float*)d_in[8];
    float* out = (float*)d_out;

    char* ws = (char*)d_ws;
    size_t SA = (((size_t)NB1 * HS * 2) + 255) & ~(size_t)255;  // 83.89 MB
    size_t SW = 307200 * 2;
    dim3 blk(256);

    if (ws_size >= 3 * SA + SW) {
        // primary: inp | y1 | y2 | weights ; h2 aliases y1 (dead after K2)
        unsigned short* inp = (unsigned short*)ws;
        unsigned short* y1  = (unsigned short*)(ws + SA);
        unsigned short* y2  = (unsigned short*)(ws + 2 * SA);
        unsigned short* wb  = (unsigned short*)(ws + 3 * SA);
        unsigned short* WiP = wb;
        unsigned short* WhP = wb + 51200;
        unsigned short* WoC = wb + 153600;
        unsigned short* h2  = y1;

        prep_w<<<1200, blk, 0, stream>>>(W_i, W_h, W_o, wb, 1);
        fused_in<<<4097, blk, 0, stream>>>(fini, WiP, WhP, inp, y1);
        fused_mid<<<4097, blk, 0, stream>>>(y1, inp, mapping, WhP, y2);
        gather_bond<<<4097, blk, 0, stream>>>(y2, inp, mapping, h2);
        fused_atom<<<2048, blk, 0, stream>>>(atomf, h2, a2b, WoC, b_o, out);
    } else {
        // fallback: round-5 fused path (h_a | h_b | weights)
        unsigned short* h_a = (unsigned short*)ws;
        unsigned short* h_b = (unsigned short*)(ws + SA);
        unsigned short* wb  = (unsigned short*)(ws + 2 * SA);
        unsigned short* WiP = wb;
        unsigned short* WhP = wb + 51200;
        unsigned short* WoA = wb + 153600;
        unsigned short* WoB = wb + 204800;

        prep_w<<<1200, blk, 0, stream>>>(W_i, W_h, W_o, wb, 0);
        bond_gemm_fb<<<2049, blk, 0, stream>>>(fini, h_a, mapping, WiP, WhP, h_a, 0);
        bond_gemm_fb<<<2049, blk, 0, stream>>>(fini, h_a, mapping, WiP, WhP, h_b, 1);
        bond_gemm_fb<<<2049, blk, 0, stream>>>(fini, h_b, mapping, WiP, WhP, h_a, 1);
        atom_gemm_fb<<<1024, blk, 0, stream>>>(atomf, h_a, a2b, WoA, WoB, b_o, out);
    }
    copy_gf<<<NMOLS * (GFD / 4) / 256, blk, 0, stream>>>((const float4*)gf, out);
}

// Round 9
// 554.154 us; speedup vs baseline: 1.0945x; 1.0945x over previous
//
#include <hip/hip_runtime.h>

typedef short bf16x8 __attribute__((ext_vector_type(8)));
typedef float f32x4 __attribute__((ext_vector_type(4)));

constexpr int NB1    = 131073;   // num_bonds + 1 (row 131072 = zero sentinel)
constexpr int SENT   = 131072;
constexpr int NATOMS = 65536;
constexpr int AFD    = 133;
constexpr int CFD    = 147;
constexpr int DH     = 300;
constexpr int GFD    = 2048;
constexpr int NMOLS  = 4096;
constexpr int OUTD   = DH + GFD; // 2348
constexpr int HS     = 320;      // h/y/inp row stride (bf16) = padded N
constexpr int KP1    = 160;      // padded CFD / AFD
constexpr int KP2    = 320;      // padded DH
constexpr int KPC    = 480;      // padded concat K for atom GEMM
constexpr int LSTR   = 328;      // LDS A-tile row stride (shorts); 328*2=656=41*16 -> 16B-aligned rows
constexpr int LSTRC  = 488;      // atom LDS row stride; 488*2=976=61*16

__device__ __forceinline__ unsigned short f2b(float f) {
    unsigned u = __float_as_uint(f);
    u += 0x7fffu + ((u >> 16) & 1u);
    return (unsigned short)(u >> 16);
}
__device__ __forceinline__ float blo(unsigned x) { return __uint_as_float(x << 16); }
__device__ __forceinline__ float bhi(unsigned x) { return __uint_as_float(x & 0xffff0000u); }
__device__ __forceinline__ unsigned pk2(float hi, float lo) {
    return ((unsigned)f2b(hi) << 16) | (unsigned)f2b(lo);
}
__device__ __forceinline__ unsigned pairsum4(unsigned a, unsigned b, unsigned c, unsigned d) {
    float lo = blo(a) + blo(b) + blo(c) + blo(d);
    float hi = bhi(a) + bhi(b) + bhi(c) + bhi(d);
    return pk2(hi, lo);
}
__device__ __forceinline__ unsigned relu_pk(unsigned u) {
    unsigned lo = (u & 0x8000u) ? 0u : (u & 0xFFFFu);
    unsigned hi = (u & 0x80000000u) ? 0u : (u & 0xFFFF0000u);
    return lo | hi;
}
__device__ __forceinline__ uint4 relu4(uint4 v) {
    v.x = relu_pk(v.x); v.y = relu_pk(v.y); v.z = relu_pk(v.z); v.w = relu_pk(v.w);
    return v;
}
__device__ __forceinline__ bf16x8 asbf(uint4 u) {
    union { uint4 u; bf16x8 b; } c; c.u = u; return c.b;
}

// ===================== PRIMARY PATH (BM=64, fragment-major B) =====================

// ---- K1: inp = fini @ Wi^T (raw); y1 = relu(inp) @ Wh^T (raw) ----
__global__ __launch_bounds__(256, 2) void fused_in(
    const float* __restrict__ fini,          // [NB1][147] fp32
    const unsigned short* __restrict__ WiF,  // frag-major [5][20][64][8]
    const unsigned short* __restrict__ WhF,  // frag-major [10][20][64][8]
    unsigned short* __restrict__ inp,        // [NB1][320] bf16 raw
    unsigned short* __restrict__ y1)         // [NB1][320] bf16 raw
{
    __shared__ __align__(16) short As[64 * LSTR];  // 41 KB
    const int tid = threadIdx.x, w = tid >> 6, lane = tid & 63;
    const int ml = lane & 15, kl = lane >> 4;
    const int m0 = blockIdx.x * 64;

    // ---- coalesced stage: fini tile -> As cols 0..159 (bf16, zero-padded) ----
#pragma unroll
    for (int i = 0; i < 20; ++i) {
        int f = tid + i * 256;                // 64 rows x 80 dword-pairs
        int row = f / 80, p = f - row * 80;
        int k = p * 2;
        int m = m0 + row;
        const float* src = fini + (size_t)(m < NB1 ? m : SENT) * CFD;
        float v0 = (k < CFD) ? src[k] : 0.f;
        float v1 = (k + 1 < CFD) ? src[k + 1] : 0.f;
        *(unsigned*)&As[row * LSTR + k] = ((unsigned)f2b(v1) << 16) | (unsigned)f2b(v0);
    }
    __syncthreads();

    f32x4 acc[4][5];
#pragma unroll
    for (int mt = 0; mt < 4; ++mt)
#pragma unroll
        for (int nt = 0; nt < 5; ++nt) acc[mt][nt] = (f32x4){0.f, 0.f, 0.f, 0.f};

    // ---- phase 1: K=160, A from LDS, B coalesced frag-major ----
#pragma unroll
    for (int c = 0; c < 5; ++c) {
        uint4 B[5];
#pragma unroll
        for (int nt = 0; nt < 5; ++nt)
            B[nt] = *(const uint4*)(WiF + (size_t)((c * 20 + w * 5 + nt) * 64 + lane) * 8);
        bf16x8 af[4];
#pragma unroll
        for (int mt = 0; mt < 4; ++mt)
            af[mt] = *(const bf16x8*)&As[(mt * 16 + ml) * LSTR + c * 32 + kl * 8];
#pragma unroll
        for (int mt = 0; mt < 4; ++mt)
#pragma unroll
            for (int nt = 0; nt < 5; ++nt)
                acc[mt][nt] = __builtin_amdgcn_mfma_f32_16x16x32_bf16(af[mt], asbf(B[nt]), acc[mt][nt], 0, 0, 0);
    }
    __syncthreads();   // done reading fini tile

    // ---- epilogue 1: acc -> As (raw bf16, full 320 cols) ----
#pragma unroll
    for (int mt = 0; mt < 4; ++mt)
#pragma unroll
        for (int reg = 0; reg < 4; ++reg) {
            int lr = mt * 16 + kl * 4 + reg;
#pragma unroll
            for (int nt = 0; nt < 5; ++nt)
                As[lr * LSTR + w * 80 + nt * 16 + ml] = (short)f2b(acc[mt][nt][reg]);
        }
    __syncthreads();

    // ---- coalesced: store inp (raw) + relu in place in LDS ----
#pragma unroll
    for (int i = 0; i < 10; ++i) {
        int f = tid + i * 256;                // 64 rows x 40 uint4
        int row = f / 40, s = f - row * 40;
        uint4 v = *(const uint4*)&As[row * LSTR + s * 8];
        int m = m0 + row;
        if (m < NB1) *(uint4*)(inp + (size_t)m * HS + s * 8) = v;
        *(uint4*)&As[row * LSTR + s * 8] = relu4(v);
    }
    __syncthreads();

    // ---- phase 2: y1 = relu-tile @ Wh^T, K=320 ----
#pragma unroll
    for (int mt = 0; mt < 4; ++mt)
#pragma unroll
        for (int nt = 0; nt < 5; ++nt) acc[mt][nt] = (f32x4){0.f, 0.f, 0.f, 0.f};
#pragma unroll
    for (int c = 0; c < 10; ++c) {
        uint4 B[5];
#pragma unroll
        for (int nt = 0; nt < 5; ++nt)
            B[nt] = *(const uint4*)(WhF + (size_t)((c * 20 + w * 5 + nt) * 64 + lane) * 8);
        bf16x8 af[4];
#pragma unroll
        for (int mt = 0; mt < 4; ++mt)
            af[mt] = *(const bf16x8*)&As[(mt * 16 + ml) * LSTR + c * 32 + kl * 8];
#pragma unroll
        for (int mt = 0; mt < 4; ++mt)
#pragma unroll
            for (int nt = 0; nt < 5; ++nt)
                acc[mt][nt] = __builtin_amdgcn_mfma_f32_16x16x32_bf16(af[mt], asbf(B[nt]), acc[mt][nt], 0, 0, 0);
    }
    __syncthreads();
#pragma unroll
    for (int mt = 0; mt < 4; ++mt)
#pragma unroll
        for (int reg = 0; reg < 4; ++reg) {
            int lr = mt * 16 + kl * 4 + reg;
#pragma unroll
            for (int nt = 0; nt < 5; ++nt)
                As[lr * LSTR + w * 80 + nt * 16 + ml] = (short)f2b(acc[mt][nt][reg]);
        }
    __syncthreads();
#pragma unroll
    for (int i = 0; i < 10; ++i) {
        int f = tid + i * 256;
        int row = f / 40, s = f - row * 40;
        int m = m0 + row;
        if (m < NB1)
            *(uint4*)(y1 + (size_t)m * HS + s * 8) = *(const uint4*)&As[row * LSTR + s * 8];
    }
}

// ---- K2: ydst = relu(inp + sum_4 ysrc[map]) @ Wh^T ----
__global__ __launch_bounds__(256, 2) void fused_mid(
    const unsigned short* __restrict__ ysrc,
    const unsigned short* __restrict__ inp,
    const int* __restrict__ mapping,
    const unsigned short* __restrict__ WhF,  // frag-major
    unsigned short* __restrict__ ydst)
{
    __shared__ __align__(16) short As[64 * LSTR];
    const int tid = threadIdx.x, w = tid >> 6, lane = tid & 63;
    const int ml = lane & 15, kl = lane >> 4;
    const int m0 = blockIdx.x * 64;

    // ---- stage h-tile (gather, inherently divergent): 4 threads/row, 10 segs ----
    {
        const int sr = tid & 63, sg = tid >> 6;
        int srow = m0 + sr;
        int crow = srow < NB1 ? srow : SENT;
        int4 mp = *(const int4*)(mapping + (size_t)crow * 4);
        const unsigned short* r0 = ysrc + (size_t)(mp.x < 0 ? SENT : mp.x) * HS;
        const unsigned short* r1 = ysrc + (size_t)(mp.y < 0 ? SENT : mp.y) * HS;
        const unsigned short* r2 = ysrc + (size_t)(mp.z < 0 ? SENT : mp.z) * HS;
        const unsigned short* r3 = ysrc + (size_t)(mp.w < 0 ? SENT : mp.w) * HS;
        const unsigned short* ip = inp + (size_t)crow * HS;
#pragma unroll
        for (int s = 0; s < 10; ++s) {
            int off = (s * 4 + sg) * 8;
            uint4 a = *(const uint4*)(r0 + off);
            uint4 b = *(const uint4*)(r1 + off);
            uint4 c = *(const uint4*)(r2 + off);
            uint4 d = *(const uint4*)(r3 + off);
            uint4 e = *(const uint4*)(ip + off);
            uint4 o;
            float lo, hi;
            lo = blo(a.x)+blo(b.x)+blo(c.x)+blo(d.x)+blo(e.x); hi = bhi(a.x)+bhi(b.x)+bhi(c.x)+bhi(d.x)+bhi(e.x);
            o.x = pk2(hi > 0.f ? hi : 0.f, lo > 0.f ? lo : 0.f);
            lo = blo(a.y)+blo(b.y)+blo(c.y)+blo(d.y)+blo(e.y); hi = bhi(a.y)+bhi(b.y)+bhi(c.y)+bhi(d.y)+bhi(e.y);
            o.y = pk2(hi > 0.f ? hi : 0.f, lo > 0.f ? lo : 0.f);
            lo = blo(a.z)+blo(b.z)+blo(c.z)+blo(d.z)+blo(e.z); hi = bhi(a.z)+bhi(b.z)+bhi(c.z)+bhi(d.z)+bhi(e.z);
            o.z = pk2(hi > 0.f ? hi : 0.f, lo > 0.f ? lo : 0.f);
            lo = blo(a.w)+blo(b.w)+blo(c.w)+blo(d.w)+blo(e.w); hi = bhi(a.w)+bhi(b.w)+bhi(c.w)+bhi(d.w)+bhi(e.w);
            o.w = pk2(hi > 0.f ? hi : 0.f, lo > 0.f ? lo : 0.f);
            *(uint4*)&As[sr * LSTR + off] = o;
        }
    }
    __syncthreads();

    f32x4 acc[4][5];
#pragma unroll
    for (int mt = 0; mt < 4; ++mt)
#pragma unroll
        for (int nt = 0; nt < 5; ++nt) acc[mt][nt] = (f32x4){0.f, 0.f, 0.f, 0.f};
#pragma unroll
    for (int c = 0; c < 10; ++c) {
        uint4 B[5];
#pragma unroll
        for (int nt = 0; nt < 5; ++nt)
            B[nt] = *(const uint4*)(WhF + (size_t)((c * 20 + w * 5 + nt) * 64 + lane) * 8);
        bf16x8 af[4];
#pragma unroll
        for (int mt = 0; mt < 4; ++mt)
            af[mt] = *(const bf16x8*)&As[(mt * 16 + ml) * LSTR + c * 32 + kl * 8];
#pragma unroll
        for (int mt = 0; mt < 4; ++mt)
#pragma unroll
            for (int nt = 0; nt < 5; ++nt)
                acc[mt][nt] = __builtin_amdgcn_mfma_f32_16x16x32_bf16(af[mt], asbf(B[nt]), acc[mt][nt], 0, 0, 0);
    }
    __syncthreads();
#pragma unroll
    for (int mt = 0; mt < 4; ++mt)
#pragma unroll
        for (int reg = 0; reg < 4; ++reg) {
            int lr = mt * 16 + kl * 4 + reg;
#pragma unroll
            for (int nt = 0; nt < 5; ++nt)
                As[lr * LSTR + w * 80 + nt * 16 + ml] = (short)f2b(acc[mt][nt][reg]);
        }
    __syncthreads();
#pragma unroll
    for (int i = 0; i < 10; ++i) {
        int f = tid + i * 256;
        int row = f / 40, s = f - row * 40;
        int m = m0 + row;
        if (m < NB1)
            *(uint4*)(ydst + (size_t)m * HS + s * 8) = *(const uint4*)&As[row * LSTR + s * 8];
    }
}

// ---- K3: h2 = relu(inp + sum_4 y2[map]) ----
__global__ __launch_bounds__(256) void gather_bond(
    const unsigned short* __restrict__ y, const unsigned short* __restrict__ inp,
    const int* __restrict__ mapping, unsigned short* __restrict__ hout)
{
    int t = blockIdx.x * 256 + threadIdx.x;
    int row = t >> 3, g = t & 7;
    if (row >= NB1) return;
    int4 mp = *(const int4*)(mapping + (size_t)row * 4);
    const unsigned short* r0 = y + (size_t)(mp.x < 0 ? SENT : mp.x) * HS;
    const unsigned short* r1 = y + (size_t)(mp.y < 0 ? SENT : mp.y) * HS;
    const unsigned short* r2 = y + (size_t)(mp.z < 0 ? SENT : mp.z) * HS;
    const unsigned short* r3 = y + (size_t)(mp.w < 0 ? SENT : mp.w) * HS;
    const unsigned short* ip = inp + (size_t)row * HS;
    unsigned short* op = hout + (size_t)row * HS;
#pragma unroll
    for (int s = 0; s < 5; ++s) {
        int off = (g + s * 8) * 8;
        uint4 a = *(const uint4*)(r0 + off);
        uint4 b = *(const uint4*)(r1 + off);
        uint4 c = *(const uint4*)(r2 + off);
        uint4 d = *(const uint4*)(r3 + off);
        uint4 e = *(const uint4*)(ip + off);
        uint4 o;
        float lo, hi;
        lo = blo(a.x)+blo(b.x)+blo(c.x)+blo(d.x)+blo(e.x); hi = bhi(a.x)+bhi(b.x)+bhi(c.x)+bhi(d.x)+bhi(e.x);
        o.x = pk2(hi > 0.f ? hi : 0.f, lo > 0.f ? lo : 0.f);
        lo = blo(a.y)+blo(b.y)+blo(c.y)+blo(d.y)+blo(e.y); hi = bhi(a.y)+bhi(b.y)+bhi(c.y)+bhi(d.y)+bhi(e.y);
        o.y = pk2(hi > 0.f ? hi : 0.f, lo > 0.f ? lo : 0.f);
        lo = blo(a.z)+blo(b.z)+blo(c.z)+blo(d.z)+blo(e.z); hi = bhi(a.z)+bhi(b.z)+bhi(c.z)+bhi(d.z)+bhi(e.z);
        o.z = pk2(hi > 0.f ? hi : 0.f, lo > 0.f ? lo : 0.f);
        lo = blo(a.w)+blo(b.w)+blo(c.w)+blo(d.w)+blo(e.w); hi = bhi(a.w)+bhi(b.w)+bhi(c.w)+bhi(d.w)+bhi(e.w);
        o.w = pk2(hi > 0.f ? hi : 0.f, lo > 0.f ? lo : 0.f);
        *(uint4*)(op + off) = o;
    }
}

// ---- K4: out[mol][0:300] = mean_16 relu([atomf | sum_4 h[a2b]] @ WoC^T + bo) ----
__global__ __launch_bounds__(256, 2) void fused_atom(
    const float* __restrict__ atomf,         // [NATOMS][133] fp32
    const unsigned short* __restrict__ h,    // [NB1][320] bf16
    const int* __restrict__ a2b,             // [NATOMS][4]
    const unsigned short* __restrict__ WoF,  // frag-major [15][20][64][8]
    const float* __restrict__ bo,            // [300]
    float* __restrict__ out)                 // [NMOLS][OUTD]
{
    __shared__ __align__(16) short As[64 * LSTRC];  // 61 KB
    const int tid = threadIdx.x, w = tid >> 6, lane = tid & 63;
    const int ml = lane & 15, kl = lane >> 4;
    const int m0 = blockIdx.x * 64;

    // ---- coalesced stage: atomf -> As cols 0..159 ----
#pragma unroll
    for (int i = 0; i < 20; ++i) {
        int f = tid + i * 256;
        int row = f / 80, p = f - row * 80;
        int k = p * 2;
        const float* src = atomf + (size_t)(m0 + row) * AFD;
        float v0 = (k < AFD) ? src[k] : 0.f;
        float v1 = (k + 1 < AFD) ? src[k + 1] : 0.f;
        *(unsigned*)&As[row * LSTRC + k] = ((unsigned)f2b(v1) << 16) | (unsigned)f2b(v0);
    }
    // ---- stage gather-sum h -> As cols 160..479 ----
    {
        const int sr = tid & 63, sg = tid >> 6;
        int row = m0 + sr;
        int4 mp = *(const int4*)(a2b + (size_t)row * 4);
        const unsigned short* r0 = h + (size_t)(mp.x < 0 ? SENT : mp.x) * HS;
        const unsigned short* r1 = h + (size_t)(mp.y < 0 ? SENT : mp.y) * HS;
        const unsigned short* r2 = h + (size_t)(mp.z < 0 ? SENT : mp.z) * HS;
        const unsigned short* r3 = h + (size_t)(mp.w < 0 ? SENT : mp.w) * HS;
#pragma unroll
        for (int s = 0; s < 10; ++s) {
            int off = (s * 4 + sg) * 8;
            uint4 a = *(const uint4*)(r0 + off);
            uint4 b = *(const uint4*)(r1 + off);
            uint4 c = *(const uint4*)(r2 + off);
            uint4 d = *(const uint4*)(r3 + off);
            uint4 o;
            o.x = pairsum4(a.x, b.x, c.x, d.x);
            o.y = pairsum4(a.y, b.y, c.y, d.y);
            o.z = pairsum4(a.z, b.z, c.z, d.z);
            o.w = pairsum4(a.w, b.w, c.w, d.w);
            *(uint4*)&As[sr * LSTRC + KP1 + off] = o;
        }
    }
    __syncthreads();

    f32x4 acc[4][5];
#pragma unroll
    for (int mt = 0; mt < 4; ++mt)
#pragma unroll
        for (int nt = 0; nt < 5; ++nt) acc[mt][nt] = (f32x4){0.f, 0.f, 0.f, 0.f};
#pragma unroll
    for (int c = 0; c < 15; ++c) {
        uint4 B[5];
#pragma unroll
        for (int nt = 0; nt < 5; ++nt)
            B[nt] = *(const uint4*)(WoF + (size_t)((c * 20 + w * 5 + nt) * 64 + lane) * 8);
        bf16x8 af[4];
#pragma unroll
        for (int mt = 0; mt < 4; ++mt)
            af[mt] = *(const bf16x8*)&As[(mt * 16 + ml) * LSTRC + c * 32 + kl * 8];
#pragma unroll
        for (int mt = 0; mt < 4; ++mt)
#pragma unroll
            for (int nt = 0; nt < 5; ++nt)
                acc[mt][nt] = __builtin_amdgcn_mfma_f32_16x16x32_bf16(af[mt], asbf(B[nt]), acc[mt][nt], 0, 0, 0);
    }

    // ---- epilogue: bias + relu + mean over each 16-row m-tile (= 1 molecule) ----
#pragma unroll
    for (int mt = 0; mt < 4; ++mt) {
        int mol = blockIdx.x * 4 + mt;
#pragma unroll
        for (int nt = 0; nt < 5; ++nt) {
            int n = w * 80 + nt * 16 + ml;
            float bias = (n < DH) ? bo[n] : 0.f;
            float s = 0.f;
#pragma unroll
            for (int reg = 0; reg < 4; ++reg) {
                float v = acc[mt][nt][reg] + bias;
                s += (v > 0.f ? v : 0.f);
            }
            s += __shfl_down(s, 32, 64);
            s += __shfl_down(s, 16, 64);
            if (kl == 0 && n < DH) out[(size_t)mol * OUTD + n] = s * (1.f / 16.f);
        }
    }
}

// ===================== FALLBACK (ws < 252 MB) =====================

__global__ __launch_bounds__(256, 3) void bond_gemm_fb(
    const float* __restrict__ fini, const unsigned short* __restrict__ hsrc,
    const int* __restrict__ mapping, const unsigned short* __restrict__ WiP,
    const unsigned short* __restrict__ WhP, unsigned short* __restrict__ hdst,
    int do_msg)
{
    const int tid = threadIdx.x, wv = tid >> 6, lane = tid & 63;
    const int ml = lane & 15, kh = lane >> 4;
    const int m0 = blockIdx.x * 64 + wv * 16;
    const int mrow = m0 + ml;
    const int mrowc = mrow < NB1 ? mrow : SENT;

    f32x4 acc[20];
#pragma unroll
    for (int nt = 0; nt < 20; ++nt) acc[nt] = (f32x4){0.f, 0.f, 0.f, 0.f};
    {
        const float* fp = fini + (size_t)mrowc * CFD;
#pragma unroll
        for (int c = 0; c < 5; ++c) {
            union { short s[8]; bf16x8 x; } u;
#pragma unroll
            for (int j = 0; j < 8; ++j) {
                int k = c * 32 + kh * 8 + j;
                u.s[j] = (short)f2b(k < CFD ? fp[k] : 0.f);
            }
            const unsigned short* bp = WiP + ml * KP1 + c * 32 + kh * 8;
#pragma unroll
            for (int nt = 0; nt < 20; ++nt)
                acc[nt] = __builtin_amdgcn_mfma_f32_16x16x32_bf16(u.x, *(const bf16x8*)(bp + nt * 16 * KP1), acc[nt], 0, 0, 0);
        }
    }
    if (do_msg) {
        int4 mp = *(const int4*)(mapping + (size_t)mrowc * 4);
        const unsigned short* g0 = hsrc + (size_t)(mp.x < 0 ? SENT : mp.x) * HS + kh * 8;
        const unsigned short* g1 = hsrc + (size_t)(mp.y < 0 ? SENT : mp.y) * HS + kh * 8;
        const unsigned short* g2 = hsrc + (size_t)(mp.z < 0 ? SENT : mp.z) * HS + kh * 8;
        const unsigned short* g3 = hsrc + (size_t)(mp.w < 0 ? SENT : mp.w) * HS + kh * 8;
#pragma unroll
        for (int c = 0; c < 10; ++c) {
            uint4 a = *(const uint4*)(g0 + c * 32);
            uint4 b = *(const uint4*)(g1 + c * 32);
            uint4 cc = *(const uint4*)(g2 + c * 32);
            uint4 d = *(const uint4*)(g3 + c * 32);
            uint4 o;
            o.x = pairsum4(a.x, b.x, cc.x, d.x);
            o.y = pairsum4(a.y, b.y, cc.y, d.y);
            o.z = pairsum4(a.z, b.z, cc.z, d.z);
            o.w = pairsum4(a.w, b.w, cc.w, d.w);
            const unsigned short* bp = WhP + ml * KP2 + c * 32 + kh * 8;
#pragma unroll
            for (int nt = 0; nt < 20; ++nt)
                acc[nt] = __builtin_amdgcn_mfma_f32_16x16x32_bf16(asbf(o), *(const bf16x8*)(bp + nt * 16 * KP2), acc[nt], 0, 0, 0);
        }
    }
#pragma unroll
    for (int nt = 0; nt < 20; ++nt) {
        int n = nt * 16 + ml;
#pragma unroll
        for (int reg = 0; reg < 4; ++reg) {
            int m = m0 + kh * 4 + reg;
            if (m < NB1) {
                float v = acc[nt][reg];
                hdst[(size_t)m * HS + n] = f2b(v > 0.f ? v : 0.f);
            }
        }
    }
}

__global__ __launch_bounds__(256, 3) void atom_gemm_fb(
    const float* __restrict__ atomf, const unsigned short* __restrict__ hsrc,
    const int* __restrict__ a2b, const unsigned short* __restrict__ WoA,
    const unsigned short* __restrict__ WoB, const float* __restrict__ bo,
    float* __restrict__ out)
{
    const int tid = threadIdx.x, wv = tid >> 6, lane = tid & 63;
    const int ml = lane & 15, kh = lane >> 4;
    const int m0 = blockIdx.x * 64 + wv * 16;
    const int arow = m0 + ml;

    f32x4 acc[20];
#pragma unroll
    for (int nt = 0; nt < 20; ++nt) acc[nt] = (f32x4){0.f, 0.f, 0.f, 0.f};
    {
        const float* fp = atomf + (size_t)arow * AFD;
#pragma unroll
        for (int c = 0; c < 5; ++c) {
            union { short s[8]; bf16x8 x; } u;
#pragma unroll
            for (int j = 0; j < 8; ++j) {
                int k = c * 32 + kh * 8 + j;
                u.s[j] = (short)f2b(k < AFD ? fp[k] : 0.f);
            }
            const unsigned short* bp = WoA + ml * KP1 + c * 32 + kh * 8;
#pragma unroll
            for (int nt = 0; nt < 20; ++nt)
                acc[nt] = __builtin_amdgcn_mfma_f32_16x16x32_bf16(u.x, *(const bf16x8*)(bp + nt * 16 * KP1), acc[nt], 0, 0, 0);
        }
    }
    {
        int4 mp = *(const int4*)(a2b + (size_t)arow * 4);
        const unsigned short* g0 = hsrc + (size_t)(mp.x < 0 ? SENT : mp.x) * HS + kh * 8;
        const unsigned short* g1 = hsrc + (size_t)(mp.y < 0 ? SENT : mp.y) * HS + kh * 8;
        const unsigned short* g2 = hsrc + (size_t)(mp.z < 0 ? SENT : mp.z) * HS + kh * 8;
        const unsigned short* g3 = hsrc + (size_t)(mp.w < 0 ? SENT : mp.w) * HS + kh * 8;
#pragma unroll
        for (int c = 0; c < 10; ++c) {
            uint4 a = *(const uint4*)(g0 + c * 32);
            uint4 b = *(const uint4*)(g1 + c * 32);
            uint4 cc = *(const uint4*)(g2 + c * 32);
            uint4 d = *(const uint4*)(g3 + c * 32);
            uint4 o;
            o.x = pairsum4(a.x, b.x, cc.x, d.x);
            o.y = pairsum4(a.y, b.y, cc.y, d.y);
            o.z = pairsum4(a.z, b.z, cc.z, d.z);
            o.w = pairsum4(a.w, b.w, cc.w, d.w);
            const unsigned short* bp = WoB + ml * KP2 + c * 32 + kh * 8;
#pragma unroll
            for (int nt = 0; nt < 20; ++nt)
                acc[nt] = __builtin_amdgcn_mfma_f32_16x16x32_bf16(asbf(o), *(const bf16x8*)(bp + nt * 16 * KP2), acc[nt], 0, 0, 0);
        }
    }
    const int mol = blockIdx.x * 4 + wv;
#pragma unroll
    for (int nt = 0; nt < 20; ++nt) {
        int n = nt * 16 + ml;
        float bias = (n < DH) ? bo[n] : 0.f;
        float s = 0.f;
#pragma unroll
        for (int reg = 0; reg < 4; ++reg) {
            float v = acc[nt][reg] + bias;
            s += (v > 0.f ? v : 0.f);
        }
        s += __shfl_down(s, 32, 64);
        s += __shfl_down(s, 16, 64);
        if (kh == 0 && n < DH) out[(size_t)mol * OUTD + n] = s * (1.f / 16.f);
    }
}

// ===================== shared prep / copy =====================

// mode=1: fragment-major (primary); mode=0: row-major padded (fallback)
__global__ void prep_w(const float* __restrict__ Wi, const float* __restrict__ Wh,
                       const float* __restrict__ Wo, unsigned short* __restrict__ wb, int mode) {
    int t = blockIdx.x * blockDim.x + threadIdx.x;
    if (t >= 307200) return;
    float v = 0.f;
    if (mode) {
        int q, nchunk_base;
        const float* W; int ld, ksz, kofs = 0;
        if (t < 51200)       { q = t;          W = Wi; ld = CFD; ksz = CFD; }
        else if (t < 153600) { q = t - 51200;  W = Wh; ld = DH;  ksz = DH;  }
        else                 { q = t - 153600; W = Wo; ld = 433; ksz = 433; kofs = 1; }
        int j = q & 7, l = (q >> 3) & 63, r = q >> 9;
        int tile = r % 20, c = r / 20;
        int ml = l & 15, kl = l >> 4;
        int n = tile * 16 + ml;
        int k = c * 32 + kl * 8 + j;
        if (n < DH) {
            if (!kofs) {
                if (k < ksz) v = W[n * ld + k];
            } else {   // Wo concat: k<AFD -> cols 0..132 ; 160<=k<460 -> cols 133..432
                if (k < AFD) v = W[n * ld + k];
                else if (k >= KP1 && k < KP1 + DH) v = W[n * ld + AFD + (k - KP1)];
            }
        }
        (void)nchunk_base;
    } else {
        if (t < 51200) {                       // WiP [320][160]
            int n = t / 160, k = t % 160;
            if (n < DH && k < CFD) v = Wi[n * CFD + k];
        } else if (t < 153600) {               // WhP [320][320]
            int q = t - 51200; int n = q / 320, k = q % 320;
            if (n < DH && k < DH) v = Wh[n * DH + k];
        } else if (t < 204800) {               // WoA [320][160]
            int q = t - 153600; int n = q / 160, k = q % 160;
            if (n < DH && k < AFD) v = Wo[n * 433 + k];
        } else {                               // WoB [320][320]
            int q = t - 204800; int n = q / 320, k = q % 320;
            if (n < DH && k < DH) v = Wo[n * 433 + AFD + k];
        }
    }
    wb[t] = f2b(v);
}

__global__ void copy_gf(const float4* __restrict__ gf, float* __restrict__ out) {
    int t = blockIdx.x * blockDim.x + threadIdx.x;
    if (t >= NMOLS * (GFD / 4)) return;
    int mol = t >> 9;
    int g4 = t & 511;
    float4 v = gf[t];
    *(float4*)(out + (size_t)mol * OUTD + DH + g4 * 4) = v;
}

extern "C" void kernel_launch(void* const* d_in, const int* in_sizes, int n_in,
                              void* d_out, int out_size, void* d_ws, size_t ws_size,
                              hipStream_t stream) {
    const float* atomf   = (const float*)d_in[0];
    const float* fini    = (const float*)d_in[1];
    const int*   a2b     = (const int*)d_in[2];
    const int*   mapping = (const int*)d_in[3];
    const float* gf      = (const float*)d_in[4];
    const float* W_i     = (const float*)d_in[5];
    const float* W_h     = (const float*)d_in[6];
    const float* W_o     = (const float*)d_in[7];
    const float* b_o     = (const float*)d_in[8];
    float* out = (float*)d_out;

    char* ws = (char*)d_ws;
    size_t SA = (((size_t)NB1 * HS * 2) + 255) & ~(size_t)255;  // 83.89 MB
    size_t SW = 307200 * 2;
    dim3 blk(256);

    if (ws_size >= 3 * SA + SW) {
        // primary: inp | y1 | y2 | weights ; h2 aliases y1 (dead after K2)
        unsigned short* inp = (unsigned short*)ws;
        unsigned short* y1  = (unsigned short*)(ws + SA);
        unsigned short* y2  = (unsigned short*)(ws + 2 * SA);
        unsigned short* wb  = (unsigned short*)(ws + 3 * SA);
        unsigned short* WiF = wb;
        unsigned short* WhF = wb + 51200;
        unsigned short* WoF = wb + 153600;
        unsigned short* h2  = y1;

        prep_w<<<1200, blk, 0, stream>>>(W_i, W_h, W_o, wb, 1);
        fused_in<<<2049, blk, 0, stream>>>(fini, WiF, WhF, inp, y1);
        fused_mid<<<2049, blk, 0, stream>>>(y1, inp, mapping, WhF, y2);
        gather_bond<<<4097, blk, 0, stream>>>(y2, inp, mapping, h2);
        fused_atom<<<1024, blk, 0, stream>>>(atomf, h2, a2b, WoF, b_o, out);
    } else {
        // fallback: fused path (h_a | h_b | weights), row-major weights
        unsigned short* h_a = (unsigned short*)ws;
        unsigned short* h_b = (unsigned short*)(ws + SA);
        unsigned short* wb  = (unsigned short*)(ws + 2 * SA);
        unsigned short* WiP = wb;
        unsigned short* WhP = wb + 51200;
        unsigned short* WoA = wb + 153600;
        unsigned short* WoB = wb + 204800;

        prep_w<<<1200, blk, 0, stream>>>(W_i, W_h, W_o, wb, 0);
        bond_gemm_fb<<<2049, blk, 0, stream>>>(fini, h_a, mapping, WiP, WhP, h_a, 0);
        bond_gemm_fb<<<2049, blk, 0, stream>>>(fini, h_a, mapping, WiP, WhP, h_b, 1);
        bond_gemm_fb<<<2049, blk, 0, stream>>>(fini, h_b, mapping, WiP, WhP, h_a, 1);
        atom_gemm_fb<<<1024, blk, 0, stream>>>(atomf, h_a, a2b, WoA, WoB, b_o, out);
    }
    copy_gf<<<NMOLS * (GFD / 4) / 256, blk, 0, stream>>>((const float4*)gf, out);
}